// Round 15
// baseline (62.178 us; speedup 1.0000x reference)
//
#include <hip/hip_runtime.h>

#define Hd 128
#define Wd 128
#define Cd 64
#define COd 64
#define Bd 4
#define HWd (Hd*Wd)

typedef __attribute__((ext_vector_type(8))) _Float16 half8;
typedef __attribute__((ext_vector_type(2))) _Float16 h2;
typedef __attribute__((ext_vector_type(4))) float    f32x4;

// Static device scratch (fp16 everywhere).
__device__ __align__(16) _Float16 g_wh[COd*576];                 // W[co][k], k=t*64+c
__device__ __align__(16) _Float16 g_woffh[16*576];               // w_off padded to 16 rows
__device__ __align__(16) unsigned short g_xt[(size_t)Bd*HWd*Cd]; // fp16 NHWC x

static __device__ __forceinline__ unsigned cvtpkh(float lo, float hi) {
    unsigned r;
    asm("v_cvt_pkrtz_f16_f32 %0, %1, %2" : "=v"(r) : "v"(lo), "v"(hi));
    return r;
}
static __device__ __forceinline__ h2 ash2(unsigned u) {
    union { unsigned u; h2 h; } x; x.u = u; return x.h;
}
static __device__ __forceinline__ unsigned ash2u(h2 h) {
    union { h2 h; unsigned u; } x; x.h = h; return x.u;
}

// Prep: [0,512) NHWC fp16 ; [512,656) W->fp16 ; [656,692) w_off padded fp16.
__global__ __launch_bounds__(256) void k_prep(const float* __restrict__ x,
                                              const float* __restrict__ weight,
                                              const float* __restrict__ w_off) {
    int bid = blockIdx.x;
    if (bid < 512) {
        int b = bid >> 7, y = bid & 127;
        int px = threadIdx.x & 127;
        int h  = threadIdx.x >> 7;
        const float* xb = x + (size_t)b*Cd*HWd + y*Wd + px;
        unsigned short* ob = g_xt + ((size_t)(b*HWd) + y*Wd + px)*Cd + h*32;
        #pragma unroll
        for (int oct = 0; oct < 4; ++oct) {
            unsigned pk[4];
            #pragma unroll
            for (int e = 0; e < 4; ++e) {
                float v0 = xb[(size_t)(h*32 + oct*8 + 2*e    )*HWd];
                float v1 = xb[(size_t)(h*32 + oct*8 + 2*e + 1)*HWd];
                pk[e] = cvtpkh(v0, v1);
            }
            *(uint4*)(ob + oct*8) = make_uint4(pk[0], pk[1], pk[2], pk[3]);
        }
    } else if (bid < 656) {
        int g = (bid - 512)*256 + threadIdx.x;     // 64*576
        if (g < COd*576) {
            int co = g / 576, k = g % 576;
            int t = k >> 6, c = k & 63;            // k = t*64 + c
            g_wh[g] = (_Float16)weight[(co*Cd + c)*9 + t];
        }
    } else {
        int g = (bid - 656)*256 + threadIdx.x;     // 16*576 = 9216
        if (g < 16*576) {
            int row = g / 576, k = g % 576;
            int t = k >> 6, c = k & 63;
            g_woffh[g] = (row < 4) ? (_Float16)w_off[(row*Cd + c)*9 + t] : (_Float16)0.f;
        }
    }
}

#define GATHER(T, U00, U01, U10, U11, H00, H01, H10, H11)                         \
    {                                                                             \
        float ys = (float)(i - 1) + (float)((T)/3 - 1)*s1v + off0;                \
        float xs = (float)(jA - 1) + (float)((T)%3 - 1)*s2v + off1;               \
        float y0f = floorf(ys), x0f = floorf(xs);                                 \
        float wy = ys - y0f, wx = xs - x0f;                                       \
        float vy0 = (y0f >=  0.f && y0f <= 127.f) ? 1.f : 0.f;                    \
        float vy1 = (y0f >= -1.f && y0f <= 126.f) ? 1.f : 0.f;                    \
        float vx0 = (x0f >=  0.f && x0f <= 127.f) ? 1.f : 0.f;                    \
        float vx1 = (x0f >= -1.f && x0f <= 126.f) ? 1.f : 0.f;                    \
        float w00 = (1.f-wy)*(1.f-wx)*vy0*vx0, w01 = (1.f-wy)*wx*vy0*vx1;         \
        float w10 = wy*(1.f-wx)*vy1*vx0,       w11 = wy*wx*vy1*vx1;               \
        H00 = ash2(cvtpkh(w00, w00)); H01 = ash2(cvtpkh(w01, w01));               \
        H10 = ash2(cvtpkh(w10, w10)); H11 = ash2(cvtpkh(w11, w11));               \
        int iy0 = min(max((int)y0f,     0), 127), iy1 = min(max((int)y0f+1,0),127);\
        int ix0 = min(max((int)x0f,     0), 127), ix1 = min(max((int)x0f+1,0),127);\
        U00 = *(const uint4*)(xb + (size_t)(iy0*Wd + ix0)*Cd + oct*8);            \
        U01 = *(const uint4*)(xb + (size_t)(iy0*Wd + ix1)*Cd + oct*8);            \
        U10 = *(const uint4*)(xb + (size_t)(iy1*Wd + ix0)*Cd + oct*8);            \
        U11 = *(const uint4*)(xb + (size_t)(iy1*Wd + ix1)*Cd + oct*8);            \
    }

#define PACK_STORE(BUF, U00, U01, U10, U11, H00, H01, H10, H11)                   \
    {                                                                             \
        unsigned a00[4] = {U00.x,U00.y,U00.z,U00.w};                              \
        unsigned a01[4] = {U01.x,U01.y,U01.z,U01.w};                              \
        unsigned a10[4] = {U10.x,U10.y,U10.z,U10.w};                              \
        unsigned a11[4] = {U11.x,U11.y,U11.z,U11.w};                              \
        unsigned pk[4];                                                           \
        _Pragma("unroll")                                                         \
        for (int e = 0; e < 4; ++e) {                                             \
            h2 r = ash2(a00[e])*H00 + ash2(a01[e])*H01                            \
                 + ash2(a10[e])*H10 + ash2(a11[e])*H11;                           \
            pk[e] = ash2u(r);                                                     \
        }                                                                         \
        lds_b[(((BUF)*2 + par)*2 + nt)*64 + slotA] = make_uint4(pk[0],pk[1],pk[2],pk[3]); \
    }

// Fused deform: per-block offsets mini-GEMM head (waves 0-1, 32 px) -> LDS
// broadcast -> r11 pipelined Phase A/B. 2048 blocks x 32 px; 2 kernels total.
__global__ __launch_bounds__(256) void k_deform(const float* __restrict__ b_off,
                                                const float* __restrict__ bias,
                                                float* __restrict__ out) {
    __shared__ uint4  lds_b[2*2*2*64];   // 8 KB staging
    __shared__ float4 lds_off[32];       // per-px (off0, off1, s1, s2)
    int orig = blockIdx.x;               // 2048, XCD-banded (bijective)
    int xcd = orig & 7, slotB = orig >> 3;
    int g = xcd*2 + (slotB >> 7);
    int s = slotB & 127;
    int b = g >> 2;
    int i = (g & 3)*32 + (s >> 2);
    int j0 = (s & 3) << 5;

    int w = threadIdx.x >> 6, l = threadIdx.x & 63;
    const unsigned short* xb = g_xt + (size_t)b*HWd*Cd;

    // ---- head: offsets mini-GEMM for this block's 32 px (r9 body, waves 0-1) ----
    if (w < 2) {
        int pc = l & 15, q = l >> 4;
        int j  = j0 + w*16 + pc;
        const _Float16* arow = g_woffh + pc*576 + q*8;
        f32x4 acc = {0.f, 0.f, 0.f, 0.f};
        #pragma unroll
        for (int t = 0; t < 9; ++t) {
            int yy = i + t/3 - 1, xx = j + t%3 - 1;
            bool ok = (yy >= 0) & (yy <= 127) & (xx >= 0) & (xx <= 127);
            const unsigned short* p = xb + (size_t)(yy*Wd + xx)*Cd + q*8;
            uint4 u0 = ok ? *(const uint4*)p        : make_uint4(0,0,0,0);
            uint4 u1 = ok ? *(const uint4*)(p + 32) : make_uint4(0,0,0,0);
            half8 a0 = *(const half8*)(arow + (2*t    )*32);
            half8 a1 = *(const half8*)(arow + (2*t + 1)*32);
            acc = __builtin_amdgcn_mfma_f32_16x16x32_f16(a0, *(half8*)&u0, acc, 0, 0, 0);
            acc = __builtin_amdgcn_mfma_f32_16x16x32_f16(a1, *(half8*)&u1, acc, 0, 0, 0);
        }
        if (q == 0) {   // lanes 0..15: D rows 0..3 for pixel pc
            float o0 = acc[0] + b_off[0];
            float o1 = acc[1] + b_off[1];
            float o2 = fmaxf(acc[2] + b_off[2], 0.f) + 1.f;
            float o3 = fmaxf(acc[3] + b_off[3], 0.f) + 1.f;
            lds_off[w*16 + pc] = make_float4(o0, o1, o2, o3);
        }
    }
    __syncthreads();

    // ---- Phase-A/B identities (r11) ----
    int oct = l & 7, px8 = l >> 3;
    int pxl = w*8 + px8;                 // 0..31
    int jA  = j0 + pxl;
    int nt = pxl >> 4, pcA = pxl & 15, qA = oct & 3, par = oct >> 2;
    int slotA = (pcA ^ (qA << 1)) + (qA << 4);
    int pcB = l & 15, qB = l >> 4;
    int physl = (pcB ^ (qB << 1)) + (qB << 4);
    const _Float16* wrow = g_wh + (size_t)(w*16 + pcB)*576 + qB*8;

    float4 o4 = lds_off[pxl];
    float off0 = o4.x, off1 = o4.y, s1v = o4.z, s2v = o4.w;

    f32x4 acc0 = {0.f,0.f,0.f,0.f};
    f32x4 acc1 = {0.f,0.f,0.f,0.f};

    uint4 gc00, gc01, gc10, gc11, gn00, gn01, gn10, gn11;
    h2 hc00, hc01, hc10, hc11, hn00, hn01, hn10, hn11;

    GATHER(0, gc00, gc01, gc10, gc11, hc00, hc01, hc10, hc11);

    #pragma unroll
    for (int t = 0; t < 9; ++t) {
        if (t < 8) {
            GATHER(t+1, gn00, gn01, gn10, gn11, hn00, hn01, hn10, hn11);
        }
        PACK_STORE(t & 1, gc00, gc01, gc10, gc11, hc00, hc01, hc10, hc11);
        __syncthreads();
        {
            half8 a0 = *(const half8*)(wrow + (2*t    )*32);
            half8 a1 = *(const half8*)(wrow + (2*t + 1)*32);
            half8 b00 = *(const half8*)&lds_b[(((t&1)*2 + 0)*2 + 0)*64 + physl];
            half8 b01 = *(const half8*)&lds_b[(((t&1)*2 + 0)*2 + 1)*64 + physl];
            half8 b10 = *(const half8*)&lds_b[(((t&1)*2 + 1)*2 + 0)*64 + physl];
            half8 b11 = *(const half8*)&lds_b[(((t&1)*2 + 1)*2 + 1)*64 + physl];
            acc0 = __builtin_amdgcn_mfma_f32_16x16x32_f16(a0, b00, acc0, 0, 0, 0);
            acc1 = __builtin_amdgcn_mfma_f32_16x16x32_f16(a0, b01, acc1, 0, 0, 0);
            acc0 = __builtin_amdgcn_mfma_f32_16x16x32_f16(a1, b10, acc0, 0, 0, 0);
            acc1 = __builtin_amdgcn_mfma_f32_16x16x32_f16(a1, b11, acc1, 0, 0, 0);
        }
        if (t < 8) {
            gc00 = gn00; gc01 = gn01; gc10 = gn10; gc11 = gn11;
            hc00 = hn00; hc01 = hn01; hc10 = hn10; hc11 = hn11;
        }
    }

    // store: D col = pcB (=px), row = qB*4 + rr -> co = w*16 + qB*4 + rr
    #pragma unroll
    for (int rr = 0; rr < 4; ++rr) {
        int co = w*16 + qB*4 + rr;
        float bco = bias[co];
        size_t base = ((size_t)(b*COd + co)*Hd + i)*Wd + j0;
        out[base + pcB]      = acc0[rr] + bco;
        out[base + 16 + pcB] = acc1[rr] + bco;
    }
}

extern "C" void kernel_launch(void* const* d_in, const int* in_sizes, int n_in,
                              void* d_out, int out_size, void* d_ws, size_t ws_size,
                              hipStream_t stream) {
    const float* x      = (const float*)d_in[0];
    const float* w_off  = (const float*)d_in[1];
    const float* b_off  = (const float*)d_in[2];
    const float* weight = (const float*)d_in[3];
    const float* bias   = (const float*)d_in[4];
    float* out = (float*)d_out;

    hipLaunchKernelGGL(k_prep,   dim3(692),  dim3(256), 0, stream, x, weight, w_off);
    hipLaunchKernelGGL(k_deform, dim3(2048), dim3(256), 0, stream, b_off, bias, out);
}

// Round 16
// 51.801 us; speedup vs baseline: 1.2003x; 1.2003x over previous
//
#include <hip/hip_runtime.h>

#define Hd 128
#define Wd 128
#define Cd 64
#define COd 64
#define Bd 4
#define HWd (Hd*Wd)

typedef __attribute__((ext_vector_type(8))) _Float16 half8;
typedef __attribute__((ext_vector_type(2))) _Float16 h2;
typedef __attribute__((ext_vector_type(4))) float    f32x4;

// Static device scratch (fp16 everywhere).
__device__ __align__(16) _Float16 g_wh[COd*576];                 // W[co][k], k=t*64+c
__device__ __align__(16) _Float16 g_woffh[16*576];               // w_off padded to 16 rows
__device__ float4 g_offs[Bd*HWd];                                // (off0, off1, s1, s2)
__device__ __align__(16) unsigned short g_xt[(size_t)Bd*HWd*Cd]; // fp16 NHWC x

static __device__ __forceinline__ unsigned cvtpkh(float lo, float hi) {
    unsigned r;
    asm("v_cvt_pkrtz_f16_f32 %0, %1, %2" : "=v"(r) : "v"(lo), "v"(hi));
    return r;
}
static __device__ __forceinline__ h2 ash2(unsigned u) {
    union { unsigned u; h2 h; } x; x.u = u; return x.h;
}
static __device__ __forceinline__ unsigned ash2u(h2 h) {
    union { h2 h; unsigned u; } x; x.h = h; return x.u;
}

// Prep: [0,512) NHWC fp16 ; [512,656) W->fp16 ; [656,692) w_off padded fp16.
__global__ __launch_bounds__(256) void k_prep(const float* __restrict__ x,
                                              const float* __restrict__ weight,
                                              const float* __restrict__ w_off) {
    int bid = blockIdx.x;
    if (bid < 512) {
        int b = bid >> 7, y = bid & 127;
        int px = threadIdx.x & 127;
        int h  = threadIdx.x >> 7;
        const float* xb = x + (size_t)b*Cd*HWd + y*Wd + px;
        unsigned short* ob = g_xt + ((size_t)(b*HWd) + y*Wd + px)*Cd + h*32;
        #pragma unroll
        for (int oct = 0; oct < 4; ++oct) {
            unsigned pk[4];
            #pragma unroll
            for (int e = 0; e < 4; ++e) {
                float v0 = xb[(size_t)(h*32 + oct*8 + 2*e    )*HWd];
                float v1 = xb[(size_t)(h*32 + oct*8 + 2*e + 1)*HWd];
                pk[e] = cvtpkh(v0, v1);
            }
            *(uint4*)(ob + oct*8) = make_uint4(pk[0], pk[1], pk[2], pk[3]);
        }
    } else if (bid < 656) {
        int g = (bid - 512)*256 + threadIdx.x;     // 64*576
        if (g < COd*576) {
            int co = g / 576, k = g % 576;
            int t = k >> 6, c = k & 63;            // k = t*64 + c
            g_wh[g] = (_Float16)weight[(co*Cd + c)*9 + t];
        }
    } else {
        int g = (bid - 656)*256 + threadIdx.x;     // 16*576 = 9216
        if (g < 16*576) {
            int row = g / 576, k = g % 576;
            int t = k >> 6, c = k & 63;
            g_woffh[g] = (row < 4) ? (_Float16)w_off[(row*Cd + c)*9 + t] : (_Float16)0.f;
        }
    }
}

// Offsets conv via LDS row-staging: 512 blocks (one output row each).
// Stage rows i-1..i+1 x 128 px x 64 ch coalesced -> LDS [row][chunk][px],
// then MFMA with B-fragments from ds_read_b128.
__global__ __launch_bounds__(256) void k_offs(const float* __restrict__ b_off) {
    __shared__ uint4 lds_x[3*8*128];     // 48 KB
    int orig = blockIdx.x;               // 512, XCD-banded to match deform bands
    int xcd = orig & 7, slot = orig >> 3;          // 0..63
    int g = xcd*2 + (slot >> 5);
    int b = g >> 2;
    int i = (g & 3)*32 + (slot & 31);

    int tid = threadIdx.x;
    const unsigned short* xb = g_xt + (size_t)b*HWd*Cd;

    // ---- stage 3 rows, fully coalesced; OOB rows zero-filled ----
    #pragma unroll
    for (int rr = 0; rr < 3; ++rr) {
        int y = i + rr - 1;
        bool rv = (y >= 0) && (y <= 127);
        #pragma unroll
        for (int k = 0; k < 4; ++k) {
            int n = k*256 + tid;         // n = px*8 + c
            int px = n >> 3, c = n & 7;
            uint4 v = rv ? *(const uint4*)(xb + (size_t)(y*Wd + px)*Cd + c*8)
                         : make_uint4(0, 0, 0, 0);
            lds_x[(rr*8 + c)*128 + px] = v;
        }
    }
    __syncthreads();

    // ---- MFMA phase: wave = 2 tiles of 16 px; lane (pc,q) ----
    int w = tid >> 6, l = tid & 63;
    int pc = l & 15, q = l >> 4;
    const _Float16* arow = g_woffh + pc*576 + q*8;
    float bo0 = b_off[0], bo1 = b_off[1], bo2 = b_off[2], bo3 = b_off[3];

    #pragma unroll
    for (int tile = 0; tile < 2; ++tile) {
        int j = (w*2 + tile)*16 + pc;    // output pixel of this lane's column
        f32x4 acc = {0.f, 0.f, 0.f, 0.f};
        #pragma unroll
        for (int t = 0; t < 9; ++t) {
            int dy = t/3, dx = t%3 - 1;
            int px = j + dx;
            bool ok = (px >= 0) && (px <= 127);
            int pxc = min(max(px, 0), 127);
            uint4 u0 = lds_x[(dy*8 + q    )*128 + pxc];
            uint4 u1 = lds_x[(dy*8 + q + 4)*128 + pxc];
            if (!ok) { u0 = make_uint4(0,0,0,0); u1 = make_uint4(0,0,0,0); }
            half8 a0 = *(const half8*)(arow + (2*t    )*32);
            half8 a1 = *(const half8*)(arow + (2*t + 1)*32);
            acc = __builtin_amdgcn_mfma_f32_16x16x32_f16(a0, *(half8*)&u0, acc, 0, 0, 0);
            acc = __builtin_amdgcn_mfma_f32_16x16x32_f16(a1, *(half8*)&u1, acc, 0, 0, 0);
        }
        if (q == 0) {   // lanes 0..15: D rows 0..3 for pixel j
            float o0 = acc[0] + bo0;
            float o1 = acc[1] + bo1;
            float o2 = fmaxf(acc[2] + bo2, 0.f) + 1.f;
            float o3 = fmaxf(acc[3] + bo3, 0.f) + 1.f;
            g_offs[(b*Hd + i)*Wd + j] = make_float4(o0, o1, o2, o3);
        }
    }
}

#define GATHER(T, U00, U01, U10, U11, H00, H01, H10, H11)                         \
    {                                                                             \
        float ys = (float)(i - 1) + (float)((T)/3 - 1)*s1v + off0;                \
        float xs = (float)(jA - 1) + (float)((T)%3 - 1)*s2v + off1;               \
        float y0f = floorf(ys), x0f = floorf(xs);                                 \
        float wy = ys - y0f, wx = xs - x0f;                                       \
        float vy0 = (y0f >=  0.f && y0f <= 127.f) ? 1.f : 0.f;                    \
        float vy1 = (y0f >= -1.f && y0f <= 126.f) ? 1.f : 0.f;                    \
        float vx0 = (x0f >=  0.f && x0f <= 127.f) ? 1.f : 0.f;                    \
        float vx1 = (x0f >= -1.f && x0f <= 126.f) ? 1.f : 0.f;                    \
        float w00 = (1.f-wy)*(1.f-wx)*vy0*vx0, w01 = (1.f-wy)*wx*vy0*vx1;         \
        float w10 = wy*(1.f-wx)*vy1*vx0,       w11 = wy*wx*vy1*vx1;               \
        H00 = ash2(cvtpkh(w00, w00)); H01 = ash2(cvtpkh(w01, w01));               \
        H10 = ash2(cvtpkh(w10, w10)); H11 = ash2(cvtpkh(w11, w11));               \
        int iy0 = min(max((int)y0f,     0), 127), iy1 = min(max((int)y0f+1,0),127);\
        int ix0 = min(max((int)x0f,     0), 127), ix1 = min(max((int)x0f+1,0),127);\
        U00 = *(const uint4*)(xb + (size_t)(iy0*Wd + ix0)*Cd + oct*8);            \
        U01 = *(const uint4*)(xb + (size_t)(iy0*Wd + ix1)*Cd + oct*8);            \
        U10 = *(const uint4*)(xb + (size_t)(iy1*Wd + ix0)*Cd + oct*8);            \
        U11 = *(const uint4*)(xb + (size_t)(iy1*Wd + ix1)*Cd + oct*8);            \
    }

#define PACK_STORE(BUF, U00, U01, U10, U11, H00, H01, H10, H11)                   \
    {                                                                             \
        unsigned a00[4] = {U00.x,U00.y,U00.z,U00.w};                              \
        unsigned a01[4] = {U01.x,U01.y,U01.z,U01.w};                              \
        unsigned a10[4] = {U10.x,U10.y,U10.z,U10.w};                              \
        unsigned a11[4] = {U11.x,U11.y,U11.z,U11.w};                              \
        unsigned pk[4];                                                           \
        _Pragma("unroll")                                                         \
        for (int e = 0; e < 4; ++e) {                                             \
            h2 r = ash2(a00[e])*H00 + ash2(a01[e])*H01                            \
                 + ash2(a10[e])*H10 + ash2(a11[e])*H11;                           \
            pk[e] = ash2u(r);                                                     \
        }                                                                         \
        lds_b[(((BUF)*2 + par)*2 + nt)*64 + slotA] = make_uint4(pk[0],pk[1],pk[2],pk[3]); \
    }

// Pipelined deform (r11 body): 2048 blocks x 32 px; dbuf 8KB; 1 barrier/tap.
__global__ __launch_bounds__(256) void k_deform(const float* __restrict__ bias,
                                                float* __restrict__ out) {
    __shared__ uint4 lds_b[2*2*2*64];    // [buf][parity][half][slot] = 8 KB
    int orig = blockIdx.x;               // 2048, same banding as k_offs
    int xcd = orig & 7, slotB = orig >> 3;
    int g = xcd*2 + (slotB >> 7);
    int s = slotB & 127;
    int b = g >> 2;
    int i = (g & 3)*32 + (s >> 2);
    int j0 = (s & 3) << 5;

    int w = threadIdx.x >> 6, l = threadIdx.x & 63;
    // Phase-A identity (gather/pack)
    int oct = l & 7, px8 = l >> 3;
    int pxl = w*8 + px8;                 // 0..31
    int jA  = j0 + pxl;
    int nt = pxl >> 4, pcA = pxl & 15, qA = oct & 3, par = oct >> 2;
    int slotA = (pcA ^ (qA << 1)) + (qA << 4);
    // Phase-B identity (mfma/store)
    int pcB = l & 15, qB = l >> 4;
    int physl = (pcB ^ (qB << 1)) + (qB << 4);
    const _Float16* wrow = g_wh + (size_t)(w*16 + pcB)*576 + qB*8;

    const unsigned short* xb = g_xt + (size_t)b*HWd*Cd;
    float4 o4 = g_offs[(b*Hd + i)*Wd + jA];
    float off0 = o4.x, off1 = o4.y, s1v = o4.z, s2v = o4.w;

    f32x4 acc0 = {0.f,0.f,0.f,0.f};
    f32x4 acc1 = {0.f,0.f,0.f,0.f};

    uint4 gc00, gc01, gc10, gc11, gn00, gn01, gn10, gn11;
    h2 hc00, hc01, hc10, hc11, hn00, hn01, hn10, hn11;

    GATHER(0, gc00, gc01, gc10, gc11, hc00, hc01, hc10, hc11);

    #pragma unroll
    for (int t = 0; t < 9; ++t) {
        if (t < 8) {
            GATHER(t+1, gn00, gn01, gn10, gn11, hn00, hn01, hn10, hn11);
        }
        PACK_STORE(t & 1, gc00, gc01, gc10, gc11, hc00, hc01, hc10, hc11);
        __syncthreads();
        {
            half8 a0 = *(const half8*)(wrow + (2*t    )*32);
            half8 a1 = *(const half8*)(wrow + (2*t + 1)*32);
            half8 b00 = *(const half8*)&lds_b[(((t&1)*2 + 0)*2 + 0)*64 + physl];
            half8 b01 = *(const half8*)&lds_b[(((t&1)*2 + 0)*2 + 1)*64 + physl];
            half8 b10 = *(const half8*)&lds_b[(((t&1)*2 + 1)*2 + 0)*64 + physl];
            half8 b11 = *(const half8*)&lds_b[(((t&1)*2 + 1)*2 + 1)*64 + physl];
            acc0 = __builtin_amdgcn_mfma_f32_16x16x32_f16(a0, b00, acc0, 0, 0, 0);
            acc1 = __builtin_amdgcn_mfma_f32_16x16x32_f16(a0, b01, acc1, 0, 0, 0);
            acc0 = __builtin_amdgcn_mfma_f32_16x16x32_f16(a1, b10, acc0, 0, 0, 0);
            acc1 = __builtin_amdgcn_mfma_f32_16x16x32_f16(a1, b11, acc1, 0, 0, 0);
        }
        if (t < 8) {
            gc00 = gn00; gc01 = gn01; gc10 = gn10; gc11 = gn11;
            hc00 = hn00; hc01 = hn01; hc10 = hn10; hc11 = hn11;
        }
    }

    // store: D col = pcB (=px), row = qB*4 + rr -> co = w*16 + qB*4 + rr
    #pragma unroll
    for (int rr = 0; rr < 4; ++rr) {
        int co = w*16 + qB*4 + rr;
        float bco = bias[co];
        size_t base = ((size_t)(b*COd + co)*Hd + i)*Wd + j0;
        out[base + pcB]      = acc0[rr] + bco;
        out[base + 16 + pcB] = acc1[rr] + bco;
    }
}

extern "C" void kernel_launch(void* const* d_in, const int* in_sizes, int n_in,
                              void* d_out, int out_size, void* d_ws, size_t ws_size,
                              hipStream_t stream) {
    const float* x      = (const float*)d_in[0];
    const float* w_off  = (const float*)d_in[1];
    const float* b_off  = (const float*)d_in[2];
    const float* weight = (const float*)d_in[3];
    const float* bias   = (const float*)d_in[4];
    float* out = (float*)d_out;

    hipLaunchKernelGGL(k_prep,   dim3(692),  dim3(256), 0, stream, x, weight, w_off);
    hipLaunchKernelGGL(k_offs,   dim3(512),  dim3(256), 0, stream, b_off);
    hipLaunchKernelGGL(k_deform, dim3(2048), dim3(256), 0, stream, bias, out);
}